// Round 15
// baseline (222.340 us; speedup 1.0000x reference)
//
#include <hip/hip_runtime.h>

// Shapes: B=1, S=128, Q=256, C=256, H=8, DH=32, TOT=256. Inputs/out f32.
// Numerics: absmax 0.01953125 vs thr 0.019609 (bf16-quantization bound).
// R22: (a) revert gemm_out to R16 BN=128/1024-block form (R21's BN=256
// halved grid to 2 blk/CU -> latency loss ate the traffic win; 216 vs 212).
// (b) drop bppf: under swapped-QK the bias values bp[h][q0+ln][nt*16+
// quad*4..+3] are ALREADY a contiguous float4 in the raw bp layout (one
// base + nt*64B imm offsets/lane). Read bp directly -- same values, same
// add order -> bit-identical; prep loses its 256 permute blocks (+4MB).
// (c) prep = 160 weight-cvt blocks only.
// Config otherwise R16 (best measured 212.2): proj BK=64 2-barrier fused
// f32-A-cvt; attn 4-qt blocks, chunked QK^T + sched_barrier (96 VGPR),
// hoisted gates; swapped-operand epilogues everywhere.

typedef unsigned short u16;
typedef unsigned int   u32;
typedef float  f32x4  __attribute__((ext_vector_type(4)));
typedef __bf16 bf16x8 __attribute__((ext_vector_type(8)));

__device__ __forceinline__ float bf2f(u16 u) {
    union { u32 i; float f; } v; v.i = ((u32)u) << 16; return v.f;
}
__device__ __forceinline__ u16 f2bf(float f) {      // hw RNE cvt
    __bf16 h = (__bf16)f; return __builtin_bit_cast(u16, h);
}

// async global->LDS, 16B/lane; lds dest wave-uniform base (HW adds lane*16)
__device__ __forceinline__ void gld16(const u16* g, u16* l) {
    __builtin_amdgcn_global_load_lds(
        (const __attribute__((address_space(1))) u32*)g,
        (__attribute__((address_space(3))) u32*)l, 16, 0, 0);
}

// head-major offset for logical (row = s*256+q, col = h*32+dh)
__device__ __forceinline__ size_t hm(int row, int col) {
    const int s = row >> 8, q = row & 255, h = col >> 5, dh = col & 31;
    return ((size_t)((h * 128 + s) * 256 + q) << 5) + dh;
}

__device__ __forceinline__ void cvt8(const float4* src, u16* dst) {
    float4 a = src[0], b = src[1];
    u16 r[8];
    r[0] = f2bf(a.x); r[1] = f2bf(a.y); r[2] = f2bf(a.z); r[3] = f2bf(a.w);
    r[4] = f2bf(b.x); r[5] = f2bf(b.y); r[6] = f2bf(b.z); r[7] = f2bf(b.w);
    *(uint4*)dst = *(uint4*)r;
}

// -------------------------------------------------------------------------
// prep: f32 -> bf16 for the 5 weight mats. 160 blocks.
// -------------------------------------------------------------------------
__global__ __launch_bounds__(256) void prep(
    const float* __restrict__ Wq, const float* __restrict__ Wk,
    const float* __restrict__ Wv, const float* __restrict__ Wg,
    const float* __restrict__ Wo, u16* __restrict__ Wball)
{
    const int b = blockIdx.x, t = threadIdx.x;
    const int mat = b >> 5;              // 32 blocks per matrix
    const float* W = (mat == 0) ? Wq : (mat == 1) ? Wk : (mat == 2) ? Wv
                   : (mat == 3) ? Wg : Wo;
    const int off = (b & 31) * 2048 + t * 8;
    cvt8((const float4*)(W + off), Wball + mat * 65536 + off);
}

// -------------------------------------------------------------------------
// proj_all: fused Q/K/V/G projections, R16 structure. 2048 blocks, tile
// 128x128, BK=64. A (qx/kvx) staged from f32: reg-load float4 x2, cvt8,
// ds_write_b128. W via gld16. Operands swapped: acc = 4 consecutive dh
// -> 8-B packed stores, HEAD-MAJOR via hm().
// -------------------------------------------------------------------------
__global__ __launch_bounds__(256) void proj_all(
    const float* __restrict__ Xqf, const float* __restrict__ Xkvf,
    const u16* __restrict__ Wball, const float* __restrict__ bg,
    u16* __restrict__ Qh, u16* __restrict__ Kh, u16* __restrict__ Vh, u16* __restrict__ Gh)
{
    __shared__ u16 At[128 * 64];
    __shared__ u16 Wt[128 * 64];     // unpadded: required by global_load_lds

    const int bid = blockIdx.x;
    const int mb  = bid & 255;
    const int nb  = bid >> 8;        // 0..7
    const int t   = nb >> 1;         // 0=Q 1=K 2=V 3=G
    const int n0  = (nb & 1) * 128;
    const int m0  = mb * 128;
    const float* Af = (t == 0 || t == 3) ? Xqf : Xkvf;
    const u16* W = Wball + t * 65536;
    u16*       O = (t == 0) ? Qh : (t == 1) ? Kh : (t == 2) ? Vh : Gh;

    const int tid  = threadIdx.x;
    const int lane = tid & 63;
    const int w    = tid >> 6;
    const int quad = lane >> 4;
    const int ln   = lane & 15;
    const int wm   = (w >> 1) * 64;
    const int wn   = (w & 1) * 64;
    const int lrow = lane >> 3;          // 0..7
    const int lcol = (lane & 7) * 8;     // u16 col

    f32x4 acc[4][4] = {};

    for (int k0 = 0; k0 < 256; k0 += 64) {
        __syncthreads();
        #pragma unroll
        for (int qq = 0; qq < 4; ++qq) {
            const int r = w * 32 + qq * 8;
            gld16(W + (size_t)(n0 + r + lrow) * 256 + k0 + lcol, &Wt[r * 64]);
        }
        #pragma unroll
        for (int qq = 0; qq < 4; ++qq) {
            const int r = w * 32 + qq * 8 + lrow;
            cvt8((const float4*)(Af + (size_t)(m0 + r) * 256 + k0 + lcol),
                 &At[r * 64 + lcol]);
        }
        __syncthreads();

        #pragma unroll
        for (int kk = 0; kk < 2; ++kk) {       // k ascending
            const int kc = kk * 32 + quad * 8;
            bf16x8 af[4], bfr[4];
            #pragma unroll
            for (int i = 0; i < 4; ++i)
                af[i] = __builtin_bit_cast(bf16x8, *(const uint4*)&At[(wm + i * 16 + ln) * 64 + kc]);
            #pragma unroll
            for (int j = 0; j < 4; ++j)
                bfr[j] = __builtin_bit_cast(bf16x8, *(const uint4*)&Wt[(wn + j * 16 + ln) * 64 + kc]);
            #pragma unroll
            for (int i = 0; i < 4; ++i)
                #pragma unroll
                for (int j = 0; j < 4; ++j)
                    acc[i][j] = __builtin_amdgcn_mfma_f32_16x16x32_bf16(bfr[j], af[i], acc[i][j], 0, 0, 0);
        }
    }

    const int act = (t == 3);
    #pragma unroll
    for (int i = 0; i < 4; ++i) {
        const int row = m0 + wm + i * 16 + ln;            // q-row (m)
        #pragma unroll
        for (int j = 0; j < 4; ++j) {
            const int colb = n0 + wn + j * 16 + quad * 4; // dh base (n)
            u16 r4[4];
            if (act) {
                const float4 bgv = *(const float4*)&bg[colb];
                float v0 = acc[i][j][0] + bgv.x;
                float v1 = acc[i][j][1] + bgv.y;
                float v2 = acc[i][j][2] + bgv.z;
                float v3 = acc[i][j][3] + bgv.w;
                r4[0] = f2bf(1.0f / (1.0f + __expf(-v0)));
                r4[1] = f2bf(1.0f / (1.0f + __expf(-v1)));
                r4[2] = f2bf(1.0f / (1.0f + __expf(-v2)));
                r4[3] = f2bf(1.0f / (1.0f + __expf(-v3)));
            } else {
                r4[0] = f2bf(acc[i][j][0]);
                r4[1] = f2bf(acc[i][j][1]);
                r4[2] = f2bf(acc[i][j][2]);
                r4[3] = f2bf(acc[i][j][3]);
            }
            *(uint2*)(O + hm(row, colb)) = *(const uint2*)r4;
        }
    }
}

// -------------------------------------------------------------------------
// gemm_out: out = O @ Wo^T + bo (f32 out). O is head-major (aliases Qh).
// R16 form: BM=64, BN=128 -> 1024 blocks (4 blk/CU). Operands swapped ->
// float4 stores.
// -------------------------------------------------------------------------
__global__ __launch_bounds__(256) void gemm_out(
    const u16* __restrict__ Oh, const u16* __restrict__ Wob,
    const float* __restrict__ bo, float* __restrict__ out)
{
    __shared__ u16 At[64 * 64];
    __shared__ u16 Wt[128 * 64];

    const int bid = blockIdx.x;
    const int m0  = (bid & 511) * 64;
    const int n0  = (bid >> 9) * 128;

    const int tid  = threadIdx.x;
    const int lane = tid & 63;
    const int w    = tid >> 6;
    const int quad = lane >> 4;
    const int ln   = lane & 15;
    const int wm   = (w >> 1) * 32;
    const int wn   = (w & 1) * 64;
    const int lrow = lane >> 3;
    const int lcol = (lane & 7) * 8;

    f32x4 acc[2][4] = {};

    for (int k0 = 0; k0 < 256; k0 += 64) {
        __syncthreads();
        #pragma unroll
        for (int qq = 0; qq < 2; ++qq) {
            const int r = w * 16 + qq * 8;
            gld16(Oh + hm(m0 + r + lrow, k0 + lcol), &At[r * 64]);
        }
        #pragma unroll
        for (int qq = 0; qq < 4; ++qq) {
            const int r = w * 32 + qq * 8;
            gld16(Wob + (size_t)(n0 + r + lrow) * 256 + k0 + lcol, &Wt[r * 64]);
        }
        __syncthreads();

        #pragma unroll
        for (int kk = 0; kk < 2; ++kk) {
            const int kc = kk * 32 + quad * 8;
            bf16x8 af[2], bfr[4];
            #pragma unroll
            for (int i = 0; i < 2; ++i)
                af[i] = __builtin_bit_cast(bf16x8, *(const uint4*)&At[(wm + i * 16 + ln) * 64 + kc]);
            #pragma unroll
            for (int j = 0; j < 4; ++j)
                bfr[j] = __builtin_bit_cast(bf16x8, *(const uint4*)&Wt[(wn + j * 16 + ln) * 64 + kc]);
            #pragma unroll
            for (int i = 0; i < 2; ++i)
                #pragma unroll
                for (int j = 0; j < 4; ++j)
                    acc[i][j] = __builtin_amdgcn_mfma_f32_16x16x32_bf16(bfr[j], af[i], acc[i][j], 0, 0, 0);
        }
    }

    #pragma unroll
    for (int i = 0; i < 2; ++i) {
        const int row = m0 + wm + i * 16 + ln;
        #pragma unroll
        for (int j = 0; j < 4; ++j) {
            const int colb = n0 + wn + j * 16 + quad * 4;
            const float4 bov = *(const float4*)&bo[colb];
            float4 o;
            o.x = acc[i][j][0] + bov.x;
            o.y = acc[i][j][1] + bov.y;
            o.z = acc[i][j][2] + bov.z;
            o.w = acc[i][j][3] + bov.w;
            *(float4*)&out[(size_t)row * 256 + colb] = o;
        }
    }
}

// -------------------------------------------------------------------------
// attn: grid (1024), one (h,s) per block, ALL 4 qt tiles per block.
// V^T + bmf staged once; K slice (16 KB) L1-hot for iq>=1.
// Swapped-QK^T: sc[nt]=mfma(K,Q); thread (quad,ln) holds
// P[q=q0+ln][kp=nt*16+quad*4+rr]. Bias read DIRECTLY from bp: the needed
// float4 bp[h][q0+ln][nt*16+quad*4..+3] is contiguous in the raw layout
// (one lane base + nt*64B imm offsets) -- same values/order as the old
// permuted bppf -> bit-identical. QK^T+bias chunked 4x4-nt with
// sched_barrier(0) pressure fences (96 VGPR, no spill).
// G-gate loads hoisted to iq start. Softmax: in-reg + 2 shfl_xor.
// P-write 16x ds_write_b64; PV = mfma(V,P); 8-B vectorized epilogue.
// O aliases Qh: wave reads only its own 16 q rows before writing them.
// -------------------------------------------------------------------------
__global__ __launch_bounds__(256, 2) void attn_kernel(
    const u16* __restrict__ Qh, const u16* __restrict__ Kh, const u16* __restrict__ Vh,
    const u16* __restrict__ Gh, const float* __restrict__ bm, const float* __restrict__ bp,
    u16* __restrict__ Oh)
{
    __shared__ u16   Vt[32][264];       // V transposed: Vt[dh][kp]
    __shared__ u16   Pl[4][16][76];     // per-wave P chunk [q-row][kp], k-width 64
    __shared__ float bmf[256];

    const int hs   = blockIdx.x;
    const int h    = hs & 7;
    const int s    = hs >> 3;
    const int tid  = threadIdx.x;
    const int lane = tid & 63;
    const int w    = tid >> 6;
    const int quad = lane >> 4;
    const int ln   = lane & 15;

    const size_t hsBase = ((size_t)(h * 128 + s) * 256) << 5;   // start of [h][s] slice

    {   // stage V^T (thread tid = key row; 64 B/thread, block-contiguous 16 KB)
        const uint4* vp = (const uint4*)(Vh + hsBase + (size_t)tid * 32);
        uint4 vv0 = vp[0], vv1 = vp[1], vv2 = vp[2], vv3 = vp[3];
        u16 tmp[32];
        *(uint4*)&tmp[0]  = vv0; *(uint4*)&tmp[8]  = vv1;
        *(uint4*)&tmp[16] = vv2; *(uint4*)&tmp[24] = vv3;
        #pragma unroll
        for (int dh = 0; dh < 32; ++dh) Vt[dh][tid] = tmp[dh];
        bmf[tid] = bm[s * 256 + tid];
    }
    __syncthreads();

    for (int iq = 0; iq < 4; ++iq) {
        const int qt = iq;
        const int q0 = qt * 64 + w * 16;

        bf16x8 aq = __builtin_bit_cast(bf16x8,
            *(const uint4*)(Qh + hsBase + (size_t)(q0 + ln) * 32 + quad * 8));

        // hoisted gate loads: consumed only in the epilogue (~full-iq hiding)
        const size_t obase = hsBase + (size_t)(q0 + ln) * 32;
        const uint2 ga = *(const uint2*)(Gh + obase + quad * 4);
        const uint2 gb = *(const uint2*)(Gh + obase + 16 + quad * 4);

        // direct bias_pair row pointer: bp[h][q0+ln][quad*4 + nt*16 + rr]
        const float* bprow = bp + ((size_t)(h * 256 + q0 + ln) * 256) + quad * 4;

        f32x4 sc[16];
        float rmax[4] = {-1e30f, -1e30f, -1e30f, -1e30f};
        #pragma unroll
        for (int c = 0; c < 4; ++c) {
            bf16x8 bk[4];
            f32x4  bv[4];
            #pragma unroll
            for (int j = 0; j < 4; ++j) {
                const int nt = c * 4 + j;
                bk[j] = __builtin_bit_cast(bf16x8,
                    *(const uint4*)(Kh + hsBase + (size_t)(nt * 16 + ln) * 32 + quad * 8));
                bv[j] = *(const f32x4*)(bprow + nt * 16);
            }
            #pragma unroll
            for (int j = 0; j < 4; ++j) {
                const int nt = c * 4 + j;
                f32x4 z = {0.f, 0.f, 0.f, 0.f};
                f32x4 r = __builtin_amdgcn_mfma_f32_16x16x32_bf16(bk[j], aq, z, 0, 0, 0);
                const f32x4 bm4 = *(const f32x4*)&bmf[nt * 16 + quad * 4];
                #pragma unroll
                for (int rr = 0; rr < 4; ++rr) {
                    float v = r[rr] + bm4[rr] + bv[j][rr];
                    sc[nt][rr] = v;
                    rmax[rr] = fmaxf(rmax[rr], v);
                }
            }
            __builtin_amdgcn_sched_barrier(0);   // pressure fence: recycle bk/bv
        }

        // row max for q = q0+ln: in-reg pairs (kp bits 0-1) + quads (bits 2-3)
        float m = fmaxf(fmaxf(rmax[0], rmax[1]), fmaxf(rmax[2], rmax[3]));
        m = fmaxf(m, __shfl_xor(m, 16));
        m = fmaxf(m, __shfl_xor(m, 32));

        float s4[4] = {0.f, 0.f, 0.f, 0.f};
        #pragma unroll
        for (int nt = 0; nt < 16; ++nt)
            #pragma unroll
            for (int rr = 0; rr < 4; ++rr) {
                float p = __expf(sc[nt][rr] - m);
                sc[nt][rr] = p;
                s4[rr] += p;
            }
        // sum tree: (s0+s1)+(s2+s3), xor16, xor32 (HW-validated numerics)
        float tsum = (s4[0] + s4[1]) + (s4[2] + s4[3]);
        tsum += __shfl_xor(tsum, 16);
        tsum += __shfl_xor(tsum, 32);
        const float rinv = 1.0f / tsum;

        // chunked P-write + PV (k ascending, same accumulation order)
        f32x4 o0 = {0.f, 0.f, 0.f, 0.f}, o1 = {0.f, 0.f, 0.f, 0.f};
        #pragma unroll
        for (int c = 0; c < 4; ++c) {
            #pragma unroll
            for (int ntl = 0; ntl < 4; ++ntl) {
                const int nt = c * 4 + ntl;
                u16 r4[4];
                #pragma unroll
                for (int rr = 0; rr < 4; ++rr)
                    r4[rr] = f2bf(sc[nt][rr] * rinv);
                *(uint2*)&Pl[w][ln][ntl * 16 + quad * 4] = *(const uint2*)r4;
            }
            #pragma unroll
            for (int kcl = 0; kcl < 2; ++kcl) {
                bf16x8 pa = __builtin_bit_cast(bf16x8, *(const uint4*)&Pl[w][ln][kcl * 32 + quad * 8]);
                bf16x8 v0 = __builtin_bit_cast(bf16x8, *(const uint4*)&Vt[ln][c * 64 + kcl * 32 + quad * 8]);
                bf16x8 v1 = __builtin_bit_cast(bf16x8, *(const uint4*)&Vt[16 + ln][c * 64 + kcl * 32 + quad * 8]);
                o0 = __builtin_amdgcn_mfma_f32_16x16x32_bf16(v0, pa, o0, 0, 0, 0);
                o1 = __builtin_amdgcn_mfma_f32_16x16x32_bf16(v1, pa, o1, 0, 0, 0);
            }
        }

        // epilogue: thread (quad,ln): q = q0+ln, dh = quad*4+rr (+16 for o1)
        const u16* gau = (const u16*)&ga;
        const u16* gbu = (const u16*)&gb;
        u16 ra[4], rb[4];
        #pragma unroll
        for (int rr = 0; rr < 4; ++rr) {
            ra[rr] = f2bf(o0[rr] * bf2f(gau[rr]));
            rb[rr] = f2bf(o1[rr] * bf2f(gbu[rr]));
        }
        *(uint2*)(Oh + obase + quad * 4)      = *(const uint2*)ra;
        *(uint2*)(Oh + obase + 16 + quad * 4) = *(const uint2*)rb;
    }
}

// -------------------------------------------------------------------------
extern "C" void kernel_launch(void* const* d_in, const int* in_sizes, int n_in,
                              void* d_out, int out_size, void* d_ws, size_t ws_size,
                              hipStream_t stream)
{
    const float* qx  = (const float*)d_in[0];
    const float* kvx = (const float*)d_in[1];
    const float* bm  = (const float*)d_in[2];
    const float* bp  = (const float*)d_in[3];
    const float* Wq  = (const float*)d_in[4];
    const float* Wk  = (const float*)d_in[5];
    const float* Wv  = (const float*)d_in[6];
    const float* Wg  = (const float*)d_in[7];
    const float* bg  = (const float*)d_in[8];
    const float* Wo  = (const float*)d_in[9];
    const float* bo  = (const float*)d_in[10];
    float* out = (float*)d_out;

    // ws: Qh(=Oh), Kh, Vh, Gh (bf16, 16.78 MB each, head-major) + weights.
    const size_t NEL = (size_t)32768 * 256;
    u16* Qh = (u16*)d_ws;            // also Oh
    u16* Kh = Qh + NEL;
    u16* Vh = Kh + NEL;
    u16* Gh = Vh + NEL;
    u16* Wball = Gh + NEL;           // 5 * 65536 u16

    prep<<<dim3(160), dim3(256), 0, stream>>>(Wq, Wk, Wv, Wg, Wo, Wball);

    proj_all<<<dim3(2048), dim3(256), 0, stream>>>(qx, kvx, Wball, bg, Qh, Kh, Vh, Gh);

    attn_kernel<<<dim3(1024), dim3(256), 0, stream>>>(Qh, Kh, Vh, Gh, bm, bp, Qh /*Oh*/);

    gemm_out<<<dim3(1024), dim3(256), 0, stream>>>(Qh /*Oh*/, Wball + 4 * 65536, bo, out);
}

// Round 16
// 211.030 us; speedup vs baseline: 1.0536x; 1.0536x over previous
//
#include <hip/hip_runtime.h>

// Shapes: B=1, S=128, Q=256, C=256, H=8, DH=32, TOT=256. Inputs/out f32.
// Numerics: absmax 0.01953125 vs thr 0.019609 (bf16-quantization bound).
// R23: exact revert to R16 config (measured best 212.2us; R22's direct-bp
// read lost the 1KB-contiguous wave coalescing bppf provides -> 222us).
// Single new variable: T5 s_setprio(1) around attn's MFMA clusters
// (QK^T chunk + PV pair). attn waves are unsynchronized post-stage ->
// role-diverse -> the regime where T5 measured +4-7% (m191); no numerics
// or register impact.
// Config: prep 416 blocks (weights + bppf permute); proj R16 (BK=64
// 2-barrier, fused f32 A-cvt, 2048 blocks); gemm_out R16 (BN=128, 1024
// blocks); attn R16 (4-qt blocks, chunked QK^T + sched_barrier 96 VGPR,
// hoisted gates, bppf bias); swapped-operand epilogues everywhere.

typedef unsigned short u16;
typedef unsigned int   u32;
typedef float  f32x4  __attribute__((ext_vector_type(4)));
typedef __bf16 bf16x8 __attribute__((ext_vector_type(8)));

__device__ __forceinline__ float bf2f(u16 u) {
    union { u32 i; float f; } v; v.i = ((u32)u) << 16; return v.f;
}
__device__ __forceinline__ u16 f2bf(float f) {      // hw RNE cvt
    __bf16 h = (__bf16)f; return __builtin_bit_cast(u16, h);
}

// async global->LDS, 16B/lane; lds dest wave-uniform base (HW adds lane*16)
__device__ __forceinline__ void gld16(const u16* g, u16* l) {
    __builtin_amdgcn_global_load_lds(
        (const __attribute__((address_space(1))) u32*)g,
        (__attribute__((address_space(3))) u32*)l, 16, 0, 0);
}

// head-major offset for logical (row = s*256+q, col = h*32+dh)
__device__ __forceinline__ size_t hm(int row, int col) {
    const int s = row >> 8, q = row & 255, h = col >> 5, dh = col & 31;
    return ((size_t)((h * 128 + s) * 256 + q) << 5) + dh;
}

__device__ __forceinline__ void cvt8(const float4* src, u16* dst) {
    float4 a = src[0], b = src[1];
    u16 r[8];
    r[0] = f2bf(a.x); r[1] = f2bf(a.y); r[2] = f2bf(a.z); r[3] = f2bf(a.w);
    r[4] = f2bf(b.x); r[5] = f2bf(b.y); r[6] = f2bf(b.z); r[7] = f2bf(b.w);
    *(uint4*)dst = *(uint4*)r;
}

// -------------------------------------------------------------------------
// prep: f32 -> bf16 for the 5 weight mats + f32 permute of bias_pair into
// bppf[(h,qt,w)][nt][lane][rr]; lane=(quad,ln):
// value = bp[h][q = qt*64+w*16+ln][kp = nt*16+quad*4+rr]. 416 blocks.
// -------------------------------------------------------------------------
__global__ __launch_bounds__(256) void prep(
    const float* __restrict__ Wq, const float* __restrict__ Wk,
    const float* __restrict__ Wv, const float* __restrict__ Wg,
    const float* __restrict__ Wo, const float* __restrict__ bp,
    u16* __restrict__ Wball, float* __restrict__ bppf)
{
    const int b = blockIdx.x, t = threadIdx.x;
    if (b < 160) {
        const int mat = b >> 5;              // 32 blocks per matrix
        const float* W = (mat == 0) ? Wq : (mat == 1) ? Wk : (mat == 2) ? Wv
                       : (mat == 3) ? Wg : Wo;
        const int off = (b & 31) * 2048 + t * 8;
        cvt8((const float4*)(W + off), Wball + mat * 65536 + off);
    } else {
        // bias_pair permute: unit u = ((h*4+qt)*4+w)*16*64 + nt*64 + lane;
        // float4 = bp[h][q0+ln][nt*16+quad*4 .. +3] (contiguous source).
        const int b3 = b - 160;              // 0..255
        const int u0 = (b3 * 256 + t) * 2;
        #pragma unroll
        for (int k2 = 0; k2 < 2; ++k2) {
            const int u  = u0 + k2;
            const int l  = u & 63;
            const int nt = (u >> 6) & 15;
            const int tt = u >> 10;          // (h*4+qt)*4+w, 0..127
            const int ww = tt & 3, qqt = (tt >> 2) & 3, hh = tt >> 4;
            const int q  = qqt * 64 + ww * 16 + (l & 15);
            const int kp = nt * 16 + (l >> 4) * 4;
            const float4 v = *(const float4*)(bp + (size_t)(hh * 256 + q) * 256 + kp);
            *(float4*)(bppf + (size_t)u * 4) = v;
        }
    }
}

// -------------------------------------------------------------------------
// proj_all: fused Q/K/V/G projections, R16 structure. 2048 blocks, tile
// 128x128, BK=64. A (qx/kvx) staged from f32: reg-load float4 x2, cvt8,
// ds_write_b128. W via gld16. Operands swapped: acc = 4 consecutive dh
// -> 8-B packed stores, HEAD-MAJOR via hm().
// -------------------------------------------------------------------------
__global__ __launch_bounds__(256) void proj_all(
    const float* __restrict__ Xqf, const float* __restrict__ Xkvf,
    const u16* __restrict__ Wball, const float* __restrict__ bg,
    u16* __restrict__ Qh, u16* __restrict__ Kh, u16* __restrict__ Vh, u16* __restrict__ Gh)
{
    __shared__ u16 At[128 * 64];
    __shared__ u16 Wt[128 * 64];     // unpadded: required by global_load_lds

    const int bid = blockIdx.x;
    const int mb  = bid & 255;
    const int nb  = bid >> 8;        // 0..7
    const int t   = nb >> 1;         // 0=Q 1=K 2=V 3=G
    const int n0  = (nb & 1) * 128;
    const int m0  = mb * 128;
    const float* Af = (t == 0 || t == 3) ? Xqf : Xkvf;
    const u16* W = Wball + t * 65536;
    u16*       O = (t == 0) ? Qh : (t == 1) ? Kh : (t == 2) ? Vh : Gh;

    const int tid  = threadIdx.x;
    const int lane = tid & 63;
    const int w    = tid >> 6;
    const int quad = lane >> 4;
    const int ln   = lane & 15;
    const int wm   = (w >> 1) * 64;
    const int wn   = (w & 1) * 64;
    const int lrow = lane >> 3;          // 0..7
    const int lcol = (lane & 7) * 8;     // u16 col

    f32x4 acc[4][4] = {};

    for (int k0 = 0; k0 < 256; k0 += 64) {
        __syncthreads();
        #pragma unroll
        for (int qq = 0; qq < 4; ++qq) {
            const int r = w * 32 + qq * 8;
            gld16(W + (size_t)(n0 + r + lrow) * 256 + k0 + lcol, &Wt[r * 64]);
        }
        #pragma unroll
        for (int qq = 0; qq < 4; ++qq) {
            const int r = w * 32 + qq * 8 + lrow;
            cvt8((const float4*)(Af + (size_t)(m0 + r) * 256 + k0 + lcol),
                 &At[r * 64 + lcol]);
        }
        __syncthreads();

        #pragma unroll
        for (int kk = 0; kk < 2; ++kk) {       // k ascending
            const int kc = kk * 32 + quad * 8;
            bf16x8 af[4], bfr[4];
            #pragma unroll
            for (int i = 0; i < 4; ++i)
                af[i] = __builtin_bit_cast(bf16x8, *(const uint4*)&At[(wm + i * 16 + ln) * 64 + kc]);
            #pragma unroll
            for (int j = 0; j < 4; ++j)
                bfr[j] = __builtin_bit_cast(bf16x8, *(const uint4*)&Wt[(wn + j * 16 + ln) * 64 + kc]);
            #pragma unroll
            for (int i = 0; i < 4; ++i)
                #pragma unroll
                for (int j = 0; j < 4; ++j)
                    acc[i][j] = __builtin_amdgcn_mfma_f32_16x16x32_bf16(bfr[j], af[i], acc[i][j], 0, 0, 0);
        }
    }

    const int act = (t == 3);
    #pragma unroll
    for (int i = 0; i < 4; ++i) {
        const int row = m0 + wm + i * 16 + ln;            // q-row (m)
        #pragma unroll
        for (int j = 0; j < 4; ++j) {
            const int colb = n0 + wn + j * 16 + quad * 4; // dh base (n)
            u16 r4[4];
            if (act) {
                const float4 bgv = *(const float4*)&bg[colb];
                float v0 = acc[i][j][0] + bgv.x;
                float v1 = acc[i][j][1] + bgv.y;
                float v2 = acc[i][j][2] + bgv.z;
                float v3 = acc[i][j][3] + bgv.w;
                r4[0] = f2bf(1.0f / (1.0f + __expf(-v0)));
                r4[1] = f2bf(1.0f / (1.0f + __expf(-v1)));
                r4[2] = f2bf(1.0f / (1.0f + __expf(-v2)));
                r4[3] = f2bf(1.0f / (1.0f + __expf(-v3)));
            } else {
                r4[0] = f2bf(acc[i][j][0]);
                r4[1] = f2bf(acc[i][j][1]);
                r4[2] = f2bf(acc[i][j][2]);
                r4[3] = f2bf(acc[i][j][3]);
            }
            *(uint2*)(O + hm(row, colb)) = *(const uint2*)r4;
        }
    }
}

// -------------------------------------------------------------------------
// gemm_out: out = O @ Wo^T + bo (f32 out). O is head-major (aliases Qh).
// R16 form: BM=64, BN=128 -> 1024 blocks. Operands swapped -> float4 stores.
// -------------------------------------------------------------------------
__global__ __launch_bounds__(256) void gemm_out(
    const u16* __restrict__ Oh, const u16* __restrict__ Wob,
    const float* __restrict__ bo, float* __restrict__ out)
{
    __shared__ u16 At[64 * 64];
    __shared__ u16 Wt[128 * 64];

    const int bid = blockIdx.x;
    const int m0  = (bid & 511) * 64;
    const int n0  = (bid >> 9) * 128;

    const int tid  = threadIdx.x;
    const int lane = tid & 63;
    const int w    = tid >> 6;
    const int quad = lane >> 4;
    const int ln   = lane & 15;
    const int wm   = (w >> 1) * 32;
    const int wn   = (w & 1) * 64;
    const int lrow = lane >> 3;
    const int lcol = (lane & 7) * 8;

    f32x4 acc[2][4] = {};

    for (int k0 = 0; k0 < 256; k0 += 64) {
        __syncthreads();
        #pragma unroll
        for (int qq = 0; qq < 2; ++qq) {
            const int r = w * 16 + qq * 8;
            gld16(Oh + hm(m0 + r + lrow, k0 + lcol), &At[r * 64]);
        }
        #pragma unroll
        for (int qq = 0; qq < 4; ++qq) {
            const int r = w * 32 + qq * 8;
            gld16(Wob + (size_t)(n0 + r + lrow) * 256 + k0 + lcol, &Wt[r * 64]);
        }
        __syncthreads();

        #pragma unroll
        for (int kk = 0; kk < 2; ++kk) {
            const int kc = kk * 32 + quad * 8;
            bf16x8 af[2], bfr[4];
            #pragma unroll
            for (int i = 0; i < 2; ++i)
                af[i] = __builtin_bit_cast(bf16x8, *(const uint4*)&At[(wm + i * 16 + ln) * 64 + kc]);
            #pragma unroll
            for (int j = 0; j < 4; ++j)
                bfr[j] = __builtin_bit_cast(bf16x8, *(const uint4*)&Wt[(wn + j * 16 + ln) * 64 + kc]);
            #pragma unroll
            for (int i = 0; i < 2; ++i)
                #pragma unroll
                for (int j = 0; j < 4; ++j)
                    acc[i][j] = __builtin_amdgcn_mfma_f32_16x16x32_bf16(bfr[j], af[i], acc[i][j], 0, 0, 0);
        }
    }

    #pragma unroll
    for (int i = 0; i < 2; ++i) {
        const int row = m0 + wm + i * 16 + ln;
        #pragma unroll
        for (int j = 0; j < 4; ++j) {
            const int colb = n0 + wn + j * 16 + quad * 4;
            const float4 bov = *(const float4*)&bo[colb];
            float4 o;
            o.x = acc[i][j][0] + bov.x;
            o.y = acc[i][j][1] + bov.y;
            o.z = acc[i][j][2] + bov.z;
            o.w = acc[i][j][3] + bov.w;
            *(float4*)&out[(size_t)row * 256 + colb] = o;
        }
    }
}

// -------------------------------------------------------------------------
// attn: grid (1024), one (h,s) per block, ALL 4 qt tiles per block.
// V^T + bmf staged once; K slice (16 KB) L1-hot for iq>=1.
// Swapped-QK^T: sc[nt]=mfma(K,Q); thread (quad,ln) holds
// P[q=q0+ln][kp=nt*16+quad*4+rr]. QK^T+bias chunked 4x4-nt with
// sched_barrier(0) pressure fences (96 VGPR, no spill, 4-5 blk/CU).
// T5: s_setprio(1) around MFMA clusters (waves role-diverse post-stage).
// G-gate loads hoisted to iq start. Softmax: in-reg + 2 shfl_xor.
// P-write 16x ds_write_b64; PV = mfma(V,P); 8-B vectorized epilogue.
// O aliases Qh: wave reads only its own 16 q rows before writing them.
// -------------------------------------------------------------------------
__global__ __launch_bounds__(256, 2) void attn_kernel(
    const u16* __restrict__ Qh, const u16* __restrict__ Kh, const u16* __restrict__ Vh,
    const u16* __restrict__ Gh, const float* __restrict__ bm, const float* __restrict__ bppf,
    u16* __restrict__ Oh)
{
    __shared__ u16   Vt[32][264];       // V transposed: Vt[dh][kp]
    __shared__ u16   Pl[4][16][76];     // per-wave P chunk [q-row][kp], k-width 64
    __shared__ float bmf[256];

    const int hs   = blockIdx.x;
    const int h    = hs & 7;
    const int s    = hs >> 3;
    const int tid  = threadIdx.x;
    const int lane = tid & 63;
    const int w    = tid >> 6;
    const int quad = lane >> 4;
    const int ln   = lane & 15;

    const size_t hsBase = ((size_t)(h * 128 + s) * 256) << 5;   // start of [h][s] slice

    {   // stage V^T (thread tid = key row; 64 B/thread, block-contiguous 16 KB)
        const uint4* vp = (const uint4*)(Vh + hsBase + (size_t)tid * 32);
        uint4 vv0 = vp[0], vv1 = vp[1], vv2 = vp[2], vv3 = vp[3];
        u16 tmp[32];
        *(uint4*)&tmp[0]  = vv0; *(uint4*)&tmp[8]  = vv1;
        *(uint4*)&tmp[16] = vv2; *(uint4*)&tmp[24] = vv3;
        #pragma unroll
        for (int dh = 0; dh < 32; ++dh) Vt[dh][tid] = tmp[dh];
        bmf[tid] = bm[s * 256 + tid];
    }
    __syncthreads();

    for (int iq = 0; iq < 4; ++iq) {
        const int qt = iq;
        const int q0 = qt * 64 + w * 16;

        bf16x8 aq = __builtin_bit_cast(bf16x8,
            *(const uint4*)(Qh + hsBase + (size_t)(q0 + ln) * 32 + quad * 8));

        // hoisted gate loads: consumed only in the epilogue (~full-iq hiding)
        const size_t obase = hsBase + (size_t)(q0 + ln) * 32;
        const uint2 ga = *(const uint2*)(Gh + obase + quad * 4);
        const uint2 gb = *(const uint2*)(Gh + obase + 16 + quad * 4);

        const float* bpt = bppf + ((size_t)(((h * 4 + qt) * 4 + w) * 16) * 64 + lane) * 4;

        f32x4 sc[16];
        float rmax[4] = {-1e30f, -1e30f, -1e30f, -1e30f};
        #pragma unroll
        for (int c = 0; c < 4; ++c) {
            bf16x8 bk[4];
            f32x4  bv[4];
            #pragma unroll
            for (int j = 0; j < 4; ++j) {
                const int nt = c * 4 + j;
                bk[j] = __builtin_bit_cast(bf16x8,
                    *(const uint4*)(Kh + hsBase + (size_t)(nt * 16 + ln) * 32 + quad * 8));
                bv[j] = *(const f32x4*)(bpt + (size_t)nt * 256);
            }
            __builtin_amdgcn_s_setprio(1);       // T5: favor MFMA cluster
            #pragma unroll
            for (int j = 0; j < 4; ++j) {
                const int nt = c * 4 + j;
                f32x4 z = {0.f, 0.f, 0.f, 0.f};
                f32x4 r = __builtin_amdgcn_mfma_f32_16x16x32_bf16(bk[j], aq, z, 0, 0, 0);
                const f32x4 bm4 = *(const f32x4*)&bmf[nt * 16 + quad * 4];
                #pragma unroll
                for (int rr = 0; rr < 4; ++rr) {
                    float v = r[rr] + bm4[rr] + bv[j][rr];
                    sc[nt][rr] = v;
                    rmax[rr] = fmaxf(rmax[rr], v);
                }
            }
            __builtin_amdgcn_s_setprio(0);
            __builtin_amdgcn_sched_barrier(0);   // pressure fence: recycle bk/bv
        }

        // row max for q = q0+ln: in-reg pairs (kp bits 0-1) + quads (bits 2-3)
        float m = fmaxf(fmaxf(rmax[0], rmax[1]), fmaxf(rmax[2], rmax[3]));
        m = fmaxf(m, __shfl_xor(m, 16));
        m = fmaxf(m, __shfl_xor(m, 32));

        float s4[4] = {0.f, 0.f, 0.f, 0.f};
        #pragma unroll
        for (int nt = 0; nt < 16; ++nt)
            #pragma unroll
            for (int rr = 0; rr < 4; ++rr) {
                float p = __expf(sc[nt][rr] - m);
                sc[nt][rr] = p;
                s4[rr] += p;
            }
        // sum tree: (s0+s1)+(s2+s3), xor16, xor32 (HW-validated numerics)
        float tsum = (s4[0] + s4[1]) + (s4[2] + s4[3]);
        tsum += __shfl_xor(tsum, 16);
        tsum += __shfl_xor(tsum, 32);
        const float rinv = 1.0f / tsum;

        // chunked P-write + PV (k ascending, same accumulation order)
        f32x4 o0 = {0.f, 0.f, 0.f, 0.f}, o1 = {0.f, 0.f, 0.f, 0.f};
        #pragma unroll
        for (int c = 0; c < 4; ++c) {
            #pragma unroll
            for (int ntl = 0; ntl < 4; ++ntl) {
                const int nt = c * 4 + ntl;
                u16 r4[4];
                #pragma unroll
                for (int rr = 0; rr < 4; ++rr)
                    r4[rr] = f2bf(sc[nt][rr] * rinv);
                *(uint2*)&Pl[w][ln][ntl * 16 + quad * 4] = *(const uint2*)r4;
            }
            __builtin_amdgcn_s_setprio(1);       // T5: favor PV MFMA pair
            #pragma unroll
            for (int kcl = 0; kcl < 2; ++kcl) {
                bf16x8 pa = __builtin_bit_cast(bf16x8, *(const uint4*)&Pl[w][ln][kcl * 32 + quad * 8]);
                bf16x8 v0 = __builtin_bit_cast(bf16x8, *(const uint4*)&Vt[ln][c * 64 + kcl * 32 + quad * 8]);
                bf16x8 v1 = __builtin_bit_cast(bf16x8, *(const uint4*)&Vt[16 + ln][c * 64 + kcl * 32 + quad * 8]);
                o0 = __builtin_amdgcn_mfma_f32_16x16x32_bf16(v0, pa, o0, 0, 0, 0);
                o1 = __builtin_amdgcn_mfma_f32_16x16x32_bf16(v1, pa, o1, 0, 0, 0);
            }
            __builtin_amdgcn_s_setprio(0);
        }

        // epilogue: thread (quad,ln): q = q0+ln, dh = quad*4+rr (+16 for o1)
        const u16* gau = (const u16*)&ga;
        const u16* gbu = (const u16*)&gb;
        u16 ra[4], rb[4];
        #pragma unroll
        for (int rr = 0; rr < 4; ++rr) {
            ra[rr] = f2bf(o0[rr] * bf2f(gau[rr]));
            rb[rr] = f2bf(o1[rr] * bf2f(gbu[rr]));
        }
        *(uint2*)(Oh + obase + quad * 4)      = *(const uint2*)ra;
        *(uint2*)(Oh + obase + 16 + quad * 4) = *(const uint2*)rb;
    }
}

// -------------------------------------------------------------------------
extern "C" void kernel_launch(void* const* d_in, const int* in_sizes, int n_in,
                              void* d_out, int out_size, void* d_ws, size_t ws_size,
                              hipStream_t stream)
{
    const float* qx  = (const float*)d_in[0];
    const float* kvx = (const float*)d_in[1];
    const float* bm  = (const float*)d_in[2];
    const float* bp  = (const float*)d_in[3];
    const float* Wq  = (const float*)d_in[4];
    const float* Wk  = (const float*)d_in[5];
    const float* Wv  = (const float*)d_in[6];
    const float* Wg  = (const float*)d_in[7];
    const float* bg  = (const float*)d_in[8];
    const float* Wo  = (const float*)d_in[9];
    const float* bo  = (const float*)d_in[10];
    float* out = (float*)d_out;

    // ws: Qh(=Oh), Kh, Vh, Gh (bf16, 16.78 MB each, head-major) + weights
    //     + permuted f32 bias_pair (2 MB). Total ~69.9 MB.
    const size_t NEL = (size_t)32768 * 256;
    u16* Qh = (u16*)d_ws;            // also Oh
    u16* Kh = Qh + NEL;
    u16* Vh = Kh + NEL;
    u16* Gh = Vh + NEL;
    u16* Wball = Gh + NEL;           // 5 * 65536 u16
    float* bppf = (float*)(Wball + 5 * 65536);   // 524288 f32

    prep<<<dim3(416), dim3(256), 0, stream>>>(Wq, Wk, Wv, Wg, Wo, bp, Wball, bppf);

    proj_all<<<dim3(2048), dim3(256), 0, stream>>>(qx, kvx, Wball, bg, Qh, Kh, Vh, Gh);

    attn_kernel<<<dim3(1024), dim3(256), 0, stream>>>(Qh, Kh, Vh, Gh, bm, bppf, Qh /*Oh*/);

    gemm_out<<<dim3(1024), dim3(256), 0, stream>>>(Qh /*Oh*/, Wball + 4 * 65536, bo, out);
}

// Round 17
// 209.464 us; speedup vs baseline: 1.0615x; 1.0075x over previous
//
#include <hip/hip_runtime.h>

// Shapes: B=1, S=128, Q=256, C=256, H=8, DH=32, TOT=256. Inputs/out f32.
// Numerics: absmax 0.01953125 vs thr 0.019609 (bf16-quantization bound).
// R24 (on R23's best 211.0): move the bppf permute (only consumed by attn)
// out of the serial prep kernel into proj_all's grid (bid>=2048, 256 pure-
// memory blocks riding proj's latency-bound tail round). prep = 160 weight
// blocks (must precede proj). Permute code byte-identical -> bit-identical.
// Config: proj R16 (BK=64 2-barrier, fused f32 A-cvt); gemm R16 (BN=128);
// attn R16+T5 (4-qt blocks, chunked QK^T + sched_barrier 96 VGPR, hoisted
// gates, bppf bias, setprio around MFMA clusters); swapped operands all.

typedef unsigned short u16;
typedef unsigned int   u32;
typedef float  f32x4  __attribute__((ext_vector_type(4)));
typedef __bf16 bf16x8 __attribute__((ext_vector_type(8)));

__device__ __forceinline__ float bf2f(u16 u) {
    union { u32 i; float f; } v; v.i = ((u32)u) << 16; return v.f;
}
__device__ __forceinline__ u16 f2bf(float f) {      // hw RNE cvt
    __bf16 h = (__bf16)f; return __builtin_bit_cast(u16, h);
}

// async global->LDS, 16B/lane; lds dest wave-uniform base (HW adds lane*16)
__device__ __forceinline__ void gld16(const u16* g, u16* l) {
    __builtin_amdgcn_global_load_lds(
        (const __attribute__((address_space(1))) u32*)g,
        (__attribute__((address_space(3))) u32*)l, 16, 0, 0);
}

// head-major offset for logical (row = s*256+q, col = h*32+dh)
__device__ __forceinline__ size_t hm(int row, int col) {
    const int s = row >> 8, q = row & 255, h = col >> 5, dh = col & 31;
    return ((size_t)((h * 128 + s) * 256 + q) << 5) + dh;
}

__device__ __forceinline__ void cvt8(const float4* src, u16* dst) {
    float4 a = src[0], b = src[1];
    u16 r[8];
    r[0] = f2bf(a.x); r[1] = f2bf(a.y); r[2] = f2bf(a.z); r[3] = f2bf(a.w);
    r[4] = f2bf(b.x); r[5] = f2bf(b.y); r[6] = f2bf(b.z); r[7] = f2bf(b.w);
    *(uint4*)dst = *(uint4*)r;
}

// -------------------------------------------------------------------------
// prep: f32 -> bf16 for the 5 weight mats. 160 blocks (proj needs Wball).
// -------------------------------------------------------------------------
__global__ __launch_bounds__(256) void prep(
    const float* __restrict__ Wq, const float* __restrict__ Wk,
    const float* __restrict__ Wv, const float* __restrict__ Wg,
    const float* __restrict__ Wo, u16* __restrict__ Wball)
{
    const int b = blockIdx.x, t = threadIdx.x;
    const int mat = b >> 5;              // 32 blocks per matrix
    const float* W = (mat == 0) ? Wq : (mat == 1) ? Wk : (mat == 2) ? Wv
                   : (mat == 3) ? Wg : Wo;
    const int off = (b & 31) * 2048 + t * 8;
    cvt8((const float4*)(W + off), Wball + mat * 65536 + off);
}

// -------------------------------------------------------------------------
// proj_all: fused Q/K/V/G projections, R16 structure, 2048 GEMM blocks +
// 256 bppf-permute blocks (bid>=2048; bppf consumed only by attn, so the
// permute rides proj's tail round for free). Tile 128x128, BK=64.
// A (qx/kvx) staged from f32: reg-load float4 x2, cvt8, ds_write_b128.
// W via gld16. Operands swapped: acc = 4 consecutive dh -> 8-B packed
// stores, HEAD-MAJOR via hm().
// -------------------------------------------------------------------------
__global__ __launch_bounds__(256) void proj_all(
    const float* __restrict__ Xqf, const float* __restrict__ Xkvf,
    const u16* __restrict__ Wball, const float* __restrict__ bg,
    const float* __restrict__ bp,
    u16* __restrict__ Qh, u16* __restrict__ Kh, u16* __restrict__ Vh, u16* __restrict__ Gh,
    float* __restrict__ bppf)
{
    __shared__ u16 At[128 * 64];
    __shared__ u16 Wt[128 * 64];     // unpadded: required by global_load_lds

    const int bid = blockIdx.x;
    if (bid >= 2048) {
        // bias_pair permute (identical to old prep code): unit
        // u = ((h*4+qt)*4+w)*16*64 + nt*64 + lane;
        // float4 = bp[h][q0+ln][nt*16+quad*4 .. +3] (contiguous source).
        const int b3 = bid - 2048;           // 0..255
        const int t  = threadIdx.x;
        const int u0 = (b3 * 256 + t) * 2;
        #pragma unroll
        for (int k2 = 0; k2 < 2; ++k2) {
            const int u  = u0 + k2;
            const int l  = u & 63;
            const int nt = (u >> 6) & 15;
            const int tt = u >> 10;          // (h*4+qt)*4+w, 0..127
            const int ww = tt & 3, qqt = (tt >> 2) & 3, hh = tt >> 4;
            const int q  = qqt * 64 + ww * 16 + (l & 15);
            const int kp = nt * 16 + (l >> 4) * 4;
            const float4 v = *(const float4*)(bp + (size_t)(hh * 256 + q) * 256 + kp);
            *(float4*)(bppf + (size_t)u * 4) = v;
        }
        return;
    }

    const int mb  = bid & 255;
    const int nb  = bid >> 8;        // 0..7
    const int t   = nb >> 1;         // 0=Q 1=K 2=V 3=G
    const int n0  = (nb & 1) * 128;
    const int m0  = mb * 128;
    const float* Af = (t == 0 || t == 3) ? Xqf : Xkvf;
    const u16* W = Wball + t * 65536;
    u16*       O = (t == 0) ? Qh : (t == 1) ? Kh : (t == 2) ? Vh : Gh;

    const int tid  = threadIdx.x;
    const int lane = tid & 63;
    const int w    = tid >> 6;
    const int quad = lane >> 4;
    const int ln   = lane & 15;
    const int wm   = (w >> 1) * 64;
    const int wn   = (w & 1) * 64;
    const int lrow = lane >> 3;          // 0..7
    const int lcol = (lane & 7) * 8;     // u16 col

    f32x4 acc[4][4] = {};

    for (int k0 = 0; k0 < 256; k0 += 64) {
        __syncthreads();
        #pragma unroll
        for (int qq = 0; qq < 4; ++qq) {
            const int r = w * 32 + qq * 8;
            gld16(W + (size_t)(n0 + r + lrow) * 256 + k0 + lcol, &Wt[r * 64]);
        }
        #pragma unroll
        for (int qq = 0; qq < 4; ++qq) {
            const int r = w * 32 + qq * 8 + lrow;
            cvt8((const float4*)(Af + (size_t)(m0 + r) * 256 + k0 + lcol),
                 &At[r * 64 + lcol]);
        }
        __syncthreads();

        #pragma unroll
        for (int kk = 0; kk < 2; ++kk) {       // k ascending
            const int kc = kk * 32 + quad * 8;
            bf16x8 af[4], bfr[4];
            #pragma unroll
            for (int i = 0; i < 4; ++i)
                af[i] = __builtin_bit_cast(bf16x8, *(const uint4*)&At[(wm + i * 16 + ln) * 64 + kc]);
            #pragma unroll
            for (int j = 0; j < 4; ++j)
                bfr[j] = __builtin_bit_cast(bf16x8, *(const uint4*)&Wt[(wn + j * 16 + ln) * 64 + kc]);
            #pragma unroll
            for (int i = 0; i < 4; ++i)
                #pragma unroll
                for (int j = 0; j < 4; ++j)
                    acc[i][j] = __builtin_amdgcn_mfma_f32_16x16x32_bf16(bfr[j], af[i], acc[i][j], 0, 0, 0);
        }
    }

    const int act = (t == 3);
    #pragma unroll
    for (int i = 0; i < 4; ++i) {
        const int row = m0 + wm + i * 16 + ln;            // q-row (m)
        #pragma unroll
        for (int j = 0; j < 4; ++j) {
            const int colb = n0 + wn + j * 16 + quad * 4; // dh base (n)
            u16 r4[4];
            if (act) {
                const float4 bgv = *(const float4*)&bg[colb];
                float v0 = acc[i][j][0] + bgv.x;
                float v1 = acc[i][j][1] + bgv.y;
                float v2 = acc[i][j][2] + bgv.z;
                float v3 = acc[i][j][3] + bgv.w;
                r4[0] = f2bf(1.0f / (1.0f + __expf(-v0)));
                r4[1] = f2bf(1.0f / (1.0f + __expf(-v1)));
                r4[2] = f2bf(1.0f / (1.0f + __expf(-v2)));
                r4[3] = f2bf(1.0f / (1.0f + __expf(-v3)));
            } else {
                r4[0] = f2bf(acc[i][j][0]);
                r4[1] = f2bf(acc[i][j][1]);
                r4[2] = f2bf(acc[i][j][2]);
                r4[3] = f2bf(acc[i][j][3]);
            }
            *(uint2*)(O + hm(row, colb)) = *(const uint2*)r4;
        }
    }
}

// -------------------------------------------------------------------------
// gemm_out: out = O @ Wo^T + bo (f32 out). O is head-major (aliases Qh).
// R16 form: BM=64, BN=128 -> 1024 blocks. Operands swapped -> float4 stores.
// -------------------------------------------------------------------------
__global__ __launch_bounds__(256) void gemm_out(
    const u16* __restrict__ Oh, const u16* __restrict__ Wob,
    const float* __restrict__ bo, float* __restrict__ out)
{
    __shared__ u16 At[64 * 64];
    __shared__ u16 Wt[128 * 64];

    const int bid = blockIdx.x;
    const int m0  = (bid & 511) * 64;
    const int n0  = (bid >> 9) * 128;

    const int tid  = threadIdx.x;
    const int lane = tid & 63;
    const int w    = tid >> 6;
    const int quad = lane >> 4;
    const int ln   = lane & 15;
    const int wm   = (w >> 1) * 32;
    const int wn   = (w & 1) * 64;
    const int lrow = lane >> 3;
    const int lcol = (lane & 7) * 8;

    f32x4 acc[2][4] = {};

    for (int k0 = 0; k0 < 256; k0 += 64) {
        __syncthreads();
        #pragma unroll
        for (int qq = 0; qq < 2; ++qq) {
            const int r = w * 16 + qq * 8;
            gld16(Oh + hm(m0 + r + lrow, k0 + lcol), &At[r * 64]);
        }
        #pragma unroll
        for (int qq = 0; qq < 4; ++qq) {
            const int r = w * 32 + qq * 8;
            gld16(Wob + (size_t)(n0 + r + lrow) * 256 + k0 + lcol, &Wt[r * 64]);
        }
        __syncthreads();

        #pragma unroll
        for (int kk = 0; kk < 2; ++kk) {
            const int kc = kk * 32 + quad * 8;
            bf16x8 af[2], bfr[4];
            #pragma unroll
            for (int i = 0; i < 2; ++i)
                af[i] = __builtin_bit_cast(bf16x8, *(const uint4*)&At[(wm + i * 16 + ln) * 64 + kc]);
            #pragma unroll
            for (int j = 0; j < 4; ++j)
                bfr[j] = __builtin_bit_cast(bf16x8, *(const uint4*)&Wt[(wn + j * 16 + ln) * 64 + kc]);
            #pragma unroll
            for (int i = 0; i < 2; ++i)
                #pragma unroll
                for (int j = 0; j < 4; ++j)
                    acc[i][j] = __builtin_amdgcn_mfma_f32_16x16x32_bf16(bfr[j], af[i], acc[i][j], 0, 0, 0);
        }
    }

    #pragma unroll
    for (int i = 0; i < 2; ++i) {
        const int row = m0 + wm + i * 16 + ln;
        #pragma unroll
        for (int j = 0; j < 4; ++j) {
            const int colb = n0 + wn + j * 16 + quad * 4;
            const float4 bov = *(const float4*)&bo[colb];
            float4 o;
            o.x = acc[i][j][0] + bov.x;
            o.y = acc[i][j][1] + bov.y;
            o.z = acc[i][j][2] + bov.z;
            o.w = acc[i][j][3] + bov.w;
            *(float4*)&out[(size_t)row * 256 + colb] = o;
        }
    }
}

// -------------------------------------------------------------------------
// attn: grid (1024), one (h,s) per block, ALL 4 qt tiles per block.
// V^T + bmf staged once; K slice (16 KB) L1-hot for iq>=1.
// Swapped-QK^T: sc[nt]=mfma(K,Q); thread (quad,ln) holds
// P[q=q0+ln][kp=nt*16+quad*4+rr]. QK^T+bias chunked 4x4-nt with
// sched_barrier(0) pressure fences (96 VGPR, no spill, 4-5 blk/CU).
// T5: s_setprio(1) around MFMA clusters (waves role-diverse post-stage).
// G-gate loads hoisted to iq start. Softmax: in-reg + 2 shfl_xor.
// P-write 16x ds_write_b64; PV = mfma(V,P); 8-B vectorized epilogue.
// O aliases Qh: wave reads only its own 16 q rows before writing them.
// -------------------------------------------------------------------------
__global__ __launch_bounds__(256, 2) void attn_kernel(
    const u16* __restrict__ Qh, const u16* __restrict__ Kh, const u16* __restrict__ Vh,
    const u16* __restrict__ Gh, const float* __restrict__ bm, const float* __restrict__ bppf,
    u16* __restrict__ Oh)
{
    __shared__ u16   Vt[32][264];       // V transposed: Vt[dh][kp]
    __shared__ u16   Pl[4][16][76];     // per-wave P chunk [q-row][kp], k-width 64
    __shared__ float bmf[256];

    const int hs   = blockIdx.x;
    const int h    = hs & 7;
    const int s    = hs >> 3;
    const int tid  = threadIdx.x;
    const int lane = tid & 63;
    const int w    = tid >> 6;
    const int quad = lane >> 4;
    const int ln   = lane & 15;

    const size_t hsBase = ((size_t)(h * 128 + s) * 256) << 5;   // start of [h][s] slice

    {   // stage V^T (thread tid = key row; 64 B/thread, block-contiguous 16 KB)
        const uint4* vp = (const uint4*)(Vh + hsBase + (size_t)tid * 32);
        uint4 vv0 = vp[0], vv1 = vp[1], vv2 = vp[2], vv3 = vp[3];
        u16 tmp[32];
        *(uint4*)&tmp[0]  = vv0; *(uint4*)&tmp[8]  = vv1;
        *(uint4*)&tmp[16] = vv2; *(uint4*)&tmp[24] = vv3;
        #pragma unroll
        for (int dh = 0; dh < 32; ++dh) Vt[dh][tid] = tmp[dh];
        bmf[tid] = bm[s * 256 + tid];
    }
    __syncthreads();

    for (int iq = 0; iq < 4; ++iq) {
        const int qt = iq;
        const int q0 = qt * 64 + w * 16;

        bf16x8 aq = __builtin_bit_cast(bf16x8,
            *(const uint4*)(Qh + hsBase + (size_t)(q0 + ln) * 32 + quad * 8));

        // hoisted gate loads: consumed only in the epilogue (~full-iq hiding)
        const size_t obase = hsBase + (size_t)(q0 + ln) * 32;
        const uint2 ga = *(const uint2*)(Gh + obase + quad * 4);
        const uint2 gb = *(const uint2*)(Gh + obase + 16 + quad * 4);

        const float* bpt = bppf + ((size_t)(((h * 4 + qt) * 4 + w) * 16) * 64 + lane) * 4;

        f32x4 sc[16];
        float rmax[4] = {-1e30f, -1e30f, -1e30f, -1e30f};
        #pragma unroll
        for (int c = 0; c < 4; ++c) {
            bf16x8 bk[4];
            f32x4  bv[4];
            #pragma unroll
            for (int j = 0; j < 4; ++j) {
                const int nt = c * 4 + j;
                bk[j] = __builtin_bit_cast(bf16x8,
                    *(const uint4*)(Kh + hsBase + (size_t)(nt * 16 + ln) * 32 + quad * 8));
                bv[j] = *(const f32x4*)(bpt + (size_t)nt * 256);
            }
            __builtin_amdgcn_s_setprio(1);       // T5: favor MFMA cluster
            #pragma unroll
            for (int j = 0; j < 4; ++j) {
                const int nt = c * 4 + j;
                f32x4 z = {0.f, 0.f, 0.f, 0.f};
                f32x4 r = __builtin_amdgcn_mfma_f32_16x16x32_bf16(bk[j], aq, z, 0, 0, 0);
                const f32x4 bm4 = *(const f32x4*)&bmf[nt * 16 + quad * 4];
                #pragma unroll
                for (int rr = 0; rr < 4; ++rr) {
                    float v = r[rr] + bm4[rr] + bv[j][rr];
                    sc[nt][rr] = v;
                    rmax[rr] = fmaxf(rmax[rr], v);
                }
            }
            __builtin_amdgcn_s_setprio(0);
            __builtin_amdgcn_sched_barrier(0);   // pressure fence: recycle bk/bv
        }

        // row max for q = q0+ln: in-reg pairs (kp bits 0-1) + quads (bits 2-3)
        float m = fmaxf(fmaxf(rmax[0], rmax[1]), fmaxf(rmax[2], rmax[3]));
        m = fmaxf(m, __shfl_xor(m, 16));
        m = fmaxf(m, __shfl_xor(m, 32));

        float s4[4] = {0.f, 0.f, 0.f, 0.f};
        #pragma unroll
        for (int nt = 0; nt < 16; ++nt)
            #pragma unroll
            for (int rr = 0; rr < 4; ++rr) {
                float p = __expf(sc[nt][rr] - m);
                sc[nt][rr] = p;
                s4[rr] += p;
            }
        // sum tree: (s0+s1)+(s2+s3), xor16, xor32 (HW-validated numerics)
        float tsum = (s4[0] + s4[1]) + (s4[2] + s4[3]);
        tsum += __shfl_xor(tsum, 16);
        tsum += __shfl_xor(tsum, 32);
        const float rinv = 1.0f / tsum;

        // chunked P-write + PV (k ascending, same accumulation order)
        f32x4 o0 = {0.f, 0.f, 0.f, 0.f}, o1 = {0.f, 0.f, 0.f, 0.f};
        #pragma unroll
        for (int c = 0; c < 4; ++c) {
            #pragma unroll
            for (int ntl = 0; ntl < 4; ++ntl) {
                const int nt = c * 4 + ntl;
                u16 r4[4];
                #pragma unroll
                for (int rr = 0; rr < 4; ++rr)
                    r4[rr] = f2bf(sc[nt][rr] * rinv);
                *(uint2*)&Pl[w][ln][ntl * 16 + quad * 4] = *(const uint2*)r4;
            }
            __builtin_amdgcn_s_setprio(1);       // T5: favor PV MFMA pair
            #pragma unroll
            for (int kcl = 0; kcl < 2; ++kcl) {
                bf16x8 pa = __builtin_bit_cast(bf16x8, *(const uint4*)&Pl[w][ln][kcl * 32 + quad * 8]);
                bf16x8 v0 = __builtin_bit_cast(bf16x8, *(const uint4*)&Vt[ln][c * 64 + kcl * 32 + quad * 8]);
                bf16x8 v1 = __builtin_bit_cast(bf16x8, *(const uint4*)&Vt[16 + ln][c * 64 + kcl * 32 + quad * 8]);
                o0 = __builtin_amdgcn_mfma_f32_16x16x32_bf16(v0, pa, o0, 0, 0, 0);
                o1 = __builtin_amdgcn_mfma_f32_16x16x32_bf16(v1, pa, o1, 0, 0, 0);
            }
            __builtin_amdgcn_s_setprio(0);
        }

        // epilogue: thread (quad,ln): q = q0+ln, dh = quad*4+rr (+16 for o1)
        const u16* gau = (const u16*)&ga;
        const u16* gbu = (const u16*)&gb;
        u16 ra[4], rb[4];
        #pragma unroll
        for (int rr = 0; rr < 4; ++rr) {
            ra[rr] = f2bf(o0[rr] * bf2f(gau[rr]));
            rb[rr] = f2bf(o1[rr] * bf2f(gbu[rr]));
        }
        *(uint2*)(Oh + obase + quad * 4)      = *(const uint2*)ra;
        *(uint2*)(Oh + obase + 16 + quad * 4) = *(const uint2*)rb;
    }
}

// -------------------------------------------------------------------------
extern "C" void kernel_launch(void* const* d_in, const int* in_sizes, int n_in,
                              void* d_out, int out_size, void* d_ws, size_t ws_size,
                              hipStream_t stream)
{
    const float* qx  = (const float*)d_in[0];
    const float* kvx = (const float*)d_in[1];
    const float* bm  = (const float*)d_in[2];
    const float* bp  = (const float*)d_in[3];
    const float* Wq  = (const float*)d_in[4];
    const float* Wk  = (const float*)d_in[5];
    const float* Wv  = (const float*)d_in[6];
    const float* Wg  = (const float*)d_in[7];
    const float* bg  = (const float*)d_in[8];
    const float* Wo  = (const float*)d_in[9];
    const float* bo  = (const float*)d_in[10];
    float* out = (float*)d_out;

    // ws: Qh(=Oh), Kh, Vh, Gh (bf16, 16.78 MB each, head-major) + weights
    //     + permuted f32 bias_pair (2 MB). Total ~69.9 MB.
    const size_t NEL = (size_t)32768 * 256;
    u16* Qh = (u16*)d_ws;            // also Oh
    u16* Kh = Qh + NEL;
    u16* Vh = Kh + NEL;
    u16* Gh = Vh + NEL;
    u16* Wball = Gh + NEL;           // 5 * 65536 u16
    float* bppf = (float*)(Wball + 5 * 65536);   // 524288 f32

    prep<<<dim3(160), dim3(256), 0, stream>>>(Wq, Wk, Wv, Wg, Wo, Wball);

    proj_all<<<dim3(2304), dim3(256), 0, stream>>>(qx, kvx, Wball, bg, bp,
                                                   Qh, Kh, Vh, Gh, bppf);

    attn_kernel<<<dim3(1024), dim3(256), 0, stream>>>(Qh, Kh, Vh, Gh, bm, bppf, Qh /*Oh*/);

    gemm_out<<<dim3(1024), dim3(256), 0, stream>>>(Qh /*Oh*/, Wball + 4 * 65536, bo, out);
}